// Round 7
// baseline (228.929 us; speedup 1.0000x reference)
//
#include <hip/hip_runtime.h>

#define TOPK 32
#define EMB 64

// ---- non-temporal helpers (streams must not evict the gather table in L2) ----
typedef float vf4 __attribute__((ext_vector_type(4)));
typedef int   vi4 __attribute__((ext_vector_type(4)));

__device__ inline float4 nt_load_f4(const float* p) {
    vf4 v = __builtin_nontemporal_load((const vf4*)p);
    return make_float4(v.x, v.y, v.z, v.w);
}
__device__ inline int4 nt_load_i4(const int* p) {
    vi4 v = __builtin_nontemporal_load((const vi4*)p);
    return make_int4(v.x, v.y, v.z, v.w);
}
__device__ inline void nt_store_f4(float* p, float4 v) {
    vf4 x = {v.x, v.y, v.z, v.w};
    __builtin_nontemporal_store(x, (vf4*)p);
}

// =====================================================================
// k0: block-partial |max| over emb. 1024 partials, no atomics (deterministic).
// =====================================================================
__global__ __launch_bounds__(256) void absmax_partial_kernel(
    const float* __restrict__ emb, float* __restrict__ partial, int total4)
{
    float m = 0.0f;
    for (int i = blockIdx.x * 256 + threadIdx.x; i < total4; i += gridDim.x * 256) {
        float4 v = nt_load_f4(emb + (size_t)i * 4);
        m = fmaxf(m, fmaxf(fmaxf(fabsf(v.x), fabsf(v.y)),
                           fmaxf(fabsf(v.z), fabsf(v.w))));
    }
    __shared__ float red[256];
    red[threadIdx.x] = m;
    __syncthreads();
    for (int s = 128; s > 0; s >>= 1) {
        if (threadIdx.x < s) red[threadIdx.x] = fmaxf(red[threadIdx.x], red[threadIdx.x + s]);
        __syncthreads();
    }
    if (threadIdx.x == 0) partial[blockIdx.x] = red[0];
}

// =====================================================================
// k1: every block redundantly reduces the 1024 partials -> global max.
//  blocks [0, a_blocks): quantize emb fp32 -> int8 (16 elems/thread)
//    emb reads NT (stream), emb8 writes TEMPORAL (pre-warms L2/L3 for gather)
//  block  a_blocks:      zero row at index N (exactly 64B) + store step
// =====================================================================
__global__ __launch_bounds__(256) void quant_kernel(
    const float* __restrict__ emb, signed char* __restrict__ emb8,
    const float* __restrict__ partial, float* __restrict__ stepOut,
    int n_nodes, int a_blocks)
{
    const int t = threadIdx.x;
    __shared__ float red[256];
    float m = fmaxf(fmaxf(partial[t], partial[t + 256]),
                    fmaxf(partial[t + 512], partial[t + 768]));
    red[t] = m;
    __syncthreads();
    for (int s = 128; s > 0; s >>= 1) {
        if (t < s) red[t] = fmaxf(red[t], red[t + s]);
        __syncthreads();
    }
    const float maxv = fmaxf(red[0], 1e-20f);
    const float inv_step = 127.0f / maxv;

    if ((int)blockIdx.x < a_blocks) {
        const int gid = blockIdx.x * 256 + t;              // 16 elems per thread
        const int total16 = n_nodes * (EMB / 16);
        if (gid < total16) {
            const float* src = emb + (size_t)gid * 16;
            unsigned int w[4];
            #pragma unroll
            for (int p = 0; p < 4; ++p) {
                float4 v = nt_load_f4(src + p * 4);
                int q0 = (int)__builtin_rintf(fminf(fmaxf(v.x * inv_step, -127.f), 127.f));
                int q1 = (int)__builtin_rintf(fminf(fmaxf(v.y * inv_step, -127.f), 127.f));
                int q2 = (int)__builtin_rintf(fminf(fmaxf(v.z * inv_step, -127.f), 127.f));
                int q3 = (int)__builtin_rintf(fminf(fmaxf(v.w * inv_step, -127.f), 127.f));
                w[p] = (unsigned int)(q0 & 0xff) | ((unsigned int)(q1 & 0xff) << 8) |
                       ((unsigned int)(q2 & 0xff) << 16) | ((unsigned int)(q3 & 0xff) << 24);
            }
            ((int4*)emb8)[gid] = make_int4((int)w[0], (int)w[1], (int)w[2], (int)w[3]);
        }
    } else {
        // zero row = 64 bytes = exactly 4 int4
        if (t < 4)
            ((int4*)(emb8 + (size_t)n_nodes * EMB))[t] = make_int4(0, 0, 0, 0);
        if (t == 0) stepOut[0] = maxv / 127.0f;
    }
}

// =====================================================================
// k2: gather. 8 lanes/node, inline mask (masked -> zero row N), 32 x 64B
// row gathers (uint2/lane, temporal), exact int32 accumulate.
// nei/wei loads and out stores are NON-TEMPORAL (single-use streams).
// =====================================================================
__global__ __launch_bounds__(256) void gather_q8_kernel(
    const signed char* __restrict__ emb8,
    const float* __restrict__ wei,
    const int*   __restrict__ nei,
    const float* __restrict__ stepPtr,
    float*       __restrict__ out,
    int n_nodes)
{
    const int tid  = blockIdx.x * 256 + threadIdx.x;
    const int n    = tid >> 3;
    const int lane = tid & 7;
    if (n >= n_nodes) return;

    const float step = stepPtr[0];
    const long base = (long)n * TOPK;
    const int4   j4 = nt_load_i4(nei + base + lane * 4);
    const float4 w4 = nt_load_f4(wei + base + lane * 4);
    int jm[4];
    jm[0] = (w4.x != 0.0f) ? j4.x : n_nodes;
    jm[1] = (w4.y != 0.0f) ? j4.y : n_nodes;
    jm[2] = (w4.z != 0.0f) ? j4.z : n_nodes;
    jm[3] = (w4.w != 0.0f) ? j4.w : n_nodes;

    int acc[8] = {0, 0, 0, 0, 0, 0, 0, 0};
    int cnt = 0;

    #pragma unroll
    for (int t2 = 0; t2 < 4; ++t2) {
        // row r = t2*8 + k lives in lane 2*t2 + (k>>2), component k&3
        int j[8];
        #pragma unroll
        for (int k = 0; k < 8; ++k)
            j[k] = __shfl(jm[k & 3], t2 * 2 + (k >> 2), 8);
        uint2 r[8];
        #pragma unroll
        for (int k = 0; k < 8; ++k)
            r[k] = *(const uint2*)(emb8 + (size_t)j[k] * EMB + lane * 8);
        #pragma unroll
        for (int k = 0; k < 8; ++k) {
            cnt += (j[k] != n_nodes) ? 1 : 0;
            const unsigned int x = r[k].x, y = r[k].y;
            acc[0] += (int)(signed char)(x & 0xff);
            acc[1] += (int)(signed char)((x >> 8) & 0xff);
            acc[2] += (int)(signed char)((x >> 16) & 0xff);
            acc[3] += ((int)x) >> 24;
            acc[4] += (int)(signed char)(y & 0xff);
            acc[5] += (int)(signed char)((y >> 8) & 0xff);
            acc[6] += (int)(signed char)((y >> 16) & 0xff);
            acc[7] += ((int)y) >> 24;
        }
    }

    const float mlt = step / ((float)cnt + 1e-12f);
    float4 o0, o1;
    o0.x = acc[0] * mlt; o0.y = acc[1] * mlt; o0.z = acc[2] * mlt; o0.w = acc[3] * mlt;
    o1.x = acc[4] * mlt; o1.y = acc[5] * mlt; o1.z = acc[6] * mlt; o1.w = acc[7] * mlt;
    float* op = out + (size_t)n * EMB + lane * 8;
    nt_store_f4(op,     o0);
    nt_store_f4(op + 4, o1);
}

// =====================================================================
// Fallback (tiny ws): verified R0 fp32 kernel
// =====================================================================
__global__ __launch_bounds__(256) void pprgo_f32_kernel(
    const float* __restrict__ emb,
    const float* __restrict__ wei,
    const int*   __restrict__ nei,
    float*       __restrict__ out,
    int n_nodes)
{
    const int tid   = blockIdx.x * blockDim.x + threadIdx.x;
    const int group = tid >> 4;
    const int lane  = tid & 15;
    if (group >= n_nodes) return;
    const long base = (long)group * TOPK;
    const float w0 = wei[base + lane];
    const float w1 = wei[base + 16 + lane];
    const int   i0 = nei[base + lane];
    const int   i1 = nei[base + 16 + lane];
    const float m0 = (w0 != 0.0f) ? 1.0f : 0.0f;
    const float m1 = (w1 != 0.0f) ? 1.0f : 0.0f;
    float4 acc = make_float4(0.f, 0.f, 0.f, 0.f);
    float  cnt = 0.0f;
    #pragma unroll 8
    for (int k = 0; k < 16; ++k) {
        const int   j0 = __shfl(i0, k, 16);
        const float a0 = __shfl(m0, k, 16);
        const float4 r0 = *(const float4*)(emb + (size_t)j0 * EMB + lane * 4);
        acc.x += a0*r0.x; acc.y += a0*r0.y; acc.z += a0*r0.z; acc.w += a0*r0.w; cnt += a0;
        const int   j1 = __shfl(i1, k, 16);
        const float a1 = __shfl(m1, k, 16);
        const float4 r1 = *(const float4*)(emb + (size_t)j1 * EMB + lane * 4);
        acc.x += a1*r1.x; acc.y += a1*r1.y; acc.z += a1*r1.z; acc.w += a1*r1.w; cnt += a1;
    }
    const float sc = 1.0f / (cnt + 1e-12f);
    float4 o;
    o.x = acc.x*sc; o.y = acc.y*sc; o.z = acc.z*sc; o.w = acc.w*sc;
    *(float4*)(out + (size_t)group * EMB + lane * 4) = o;
}

extern "C" void kernel_launch(void* const* d_in, const int* in_sizes, int n_in,
                              void* d_out, int out_size, void* d_ws, size_t ws_size,
                              hipStream_t stream) {
    const float* emb = (const float*)d_in[0];   // [N, 64] fp32
    const float* wei = (const float*)d_in[1];   // [N, 32] fp32
    const int*   nei = (const int*)d_in[2];     // [N, 32] int32
    float*       out = (float*)d_out;           // [N, 1, 64] fp32

    const int n_nodes = in_sizes[1] / TOPK;     // 200000

    const size_t emb8_bytes  = (size_t)(n_nodes + 1) * EMB;            // 12.8MB + 64B
    const size_t partial_off = (emb8_bytes + 15) & ~(size_t)15;
    const size_t need_q8     = partial_off + 1024 * sizeof(float) + 16;

    if (ws_size >= need_q8) {
        signed char* emb8    = (signed char*)d_ws;
        float*       partial = (float*)((char*)d_ws + partial_off);
        float*       stepP   = partial + 1024;

        const int total4 = n_nodes * EMB / 4;
        absmax_partial_kernel<<<1024, 256, 0, stream>>>(emb, partial, total4);

        const int a_blocks = (n_nodes * (EMB / 16) + 255) / 256;       // 3125
        quant_kernel<<<a_blocks + 1, 256, 0, stream>>>(
            emb, emb8, partial, stepP, n_nodes, a_blocks);

        const int g_blocks = (n_nodes * 8 + 255) / 256;                // 6250
        gather_q8_kernel<<<g_blocks, 256, 0, stream>>>(
            emb8, wei, nei, stepP, out, n_nodes);
    } else {
        const int threads = n_nodes * 16;
        pprgo_f32_kernel<<<(threads + 255) / 256, 256, 0, stream>>>(
            emb, wei, nei, out, n_nodes);
    }
}

// Round 8
// 224.622 us; speedup vs baseline: 1.0192x; 1.0192x over previous
//
#include <hip/hip_runtime.h>

#define TOPK 32
#define EMB 64

// ---- non-temporal helpers (single-use streams; keep gather table hot in L2) ----
typedef float vf4 __attribute__((ext_vector_type(4)));
typedef int   vi4 __attribute__((ext_vector_type(4)));

__device__ inline float4 nt_load_f4(const float* p) {
    vf4 v = __builtin_nontemporal_load((const vf4*)p);
    return make_float4(v.x, v.y, v.z, v.w);
}
__device__ inline int4 nt_load_i4(const int* p) {
    vi4 v = __builtin_nontemporal_load((const vi4*)p);
    return make_int4(v.x, v.y, v.z, v.w);
}
__device__ inline void nt_store_f4(float* p, float4 v) {
    vf4 x = {v.x, v.y, v.z, v.w};
    __builtin_nontemporal_store(x, (vf4*)p);
}

// =====================================================================
// Prep (ONE pass): per-row int8 quantization.
//  8 lanes/row; lane reads 8 floats (2xfloat4, NT), butterfly-max over 8
//  lanes -> rowmax; quantize to 8 bytes (uint2, temporal: pre-warms L2);
//  lane 0 stores scale[row] = rowmax/127.
//  Last block: 64B zero row at index N + scale[N] = 0.
// =====================================================================
__global__ __launch_bounds__(256) void prep_rowquant_kernel(
    const float* __restrict__ emb,
    signed char* __restrict__ emb8,
    float*       __restrict__ scale,
    int n_nodes, int q_blocks)
{
    if ((int)blockIdx.x < q_blocks) {
        const int tid  = blockIdx.x * 256 + threadIdx.x;
        const int row  = tid >> 3;
        const int lane = tid & 7;
        if (row >= n_nodes) return;

        const float* src = emb + (size_t)row * EMB + lane * 8;
        const float4 a = nt_load_f4(src);
        const float4 b = nt_load_f4(src + 4);

        float m = fmaxf(fmaxf(fmaxf(fabsf(a.x), fabsf(a.y)), fmaxf(fabsf(a.z), fabsf(a.w))),
                        fmaxf(fmaxf(fabsf(b.x), fabsf(b.y)), fmaxf(fabsf(b.z), fabsf(b.w))));
        m = fmaxf(m, __shfl_xor(m, 1, 8));
        m = fmaxf(m, __shfl_xor(m, 2, 8));
        m = fmaxf(m, __shfl_xor(m, 4, 8));
        const float maxv = fmaxf(m, 1e-20f);
        const float inv_step = 127.0f / maxv;

        const float f[8] = {a.x, a.y, a.z, a.w, b.x, b.y, b.z, b.w};
        unsigned int w0 = 0, w1 = 0;
        #pragma unroll
        for (int i = 0; i < 4; ++i) {
            int q = (int)__builtin_rintf(f[i] * inv_step);
            w0 |= ((unsigned int)(q & 0xff)) << (8 * i);
        }
        #pragma unroll
        for (int i = 0; i < 4; ++i) {
            int q = (int)__builtin_rintf(f[4 + i] * inv_step);
            w1 |= ((unsigned int)(q & 0xff)) << (8 * i);
        }
        *(uint2*)(emb8 + (size_t)row * EMB + lane * 8) = make_uint2(w0, w1);
        if (lane == 0) scale[row] = maxv / 127.0f;
    } else {
        if (threadIdx.x < 4)
            ((int4*)(emb8 + (size_t)n_nodes * EMB))[threadIdx.x] = make_int4(0, 0, 0, 0);
        if (threadIdx.x == 0) scale[n_nodes] = 0.0f;
    }
}

// =====================================================================
// Gather: 8 lanes/node, inline mask (masked -> zero row N), 32 x 64B row
// gathers (uint2/lane, temporal), fp32 accumulate with per-row scale
// (lane k holds scale[j[k]], broadcast by shfl). Streams are NT.
// =====================================================================
__global__ __launch_bounds__(256) void gather_q8_kernel(
    const signed char* __restrict__ emb8,
    const float* __restrict__ scale,
    const float* __restrict__ wei,
    const int*   __restrict__ nei,
    float*       __restrict__ out,
    int n_nodes)
{
    const int tid  = blockIdx.x * 256 + threadIdx.x;
    const int n    = tid >> 3;
    const int lane = tid & 7;
    if (n >= n_nodes) return;

    const long base = (long)n * TOPK;
    const int4   j4 = nt_load_i4(nei + base + lane * 4);
    const float4 w4 = nt_load_f4(wei + base + lane * 4);
    int jm[4];
    jm[0] = (w4.x != 0.0f) ? j4.x : n_nodes;
    jm[1] = (w4.y != 0.0f) ? j4.y : n_nodes;
    jm[2] = (w4.z != 0.0f) ? j4.z : n_nodes;
    jm[3] = (w4.w != 0.0f) ? j4.w : n_nodes;

    float acc[8] = {0.f, 0.f, 0.f, 0.f, 0.f, 0.f, 0.f, 0.f};
    int cnt = 0;

    #pragma unroll
    for (int t2 = 0; t2 < 4; ++t2) {
        // row r = t2*8 + k lives in lane 2*t2 + (k>>2), component k&3
        int j[8];
        #pragma unroll
        for (int k = 0; k < 8; ++k)
            j[k] = __shfl(jm[k & 3], t2 * 2 + (k >> 2), 8);
        const float scm = scale[j[lane]];       // lane's row scale (0.8MB, L2-hit)
        uint2 r[8];
        #pragma unroll
        for (int k = 0; k < 8; ++k)
            r[k] = *(const uint2*)(emb8 + (size_t)j[k] * EMB + lane * 8);
        #pragma unroll
        for (int k = 0; k < 8; ++k) {
            cnt += (j[k] != n_nodes) ? 1 : 0;
            const float sck = __shfl(scm, k, 8);
            const unsigned int x = r[k].x, y = r[k].y;
            acc[0] += sck * (float)((int)(signed char)(x & 0xff));
            acc[1] += sck * (float)((int)(signed char)((x >> 8) & 0xff));
            acc[2] += sck * (float)((int)(signed char)((x >> 16) & 0xff));
            acc[3] += sck * (float)(((int)x) >> 24);
            acc[4] += sck * (float)((int)(signed char)(y & 0xff));
            acc[5] += sck * (float)((int)(signed char)((y >> 8) & 0xff));
            acc[6] += sck * (float)((int)(signed char)((y >> 16) & 0xff));
            acc[7] += sck * (float)(((int)y) >> 24);
        }
    }

    const float mlt = 1.0f / ((float)cnt + 1e-12f);
    float4 o0, o1;
    o0.x = acc[0] * mlt; o0.y = acc[1] * mlt; o0.z = acc[2] * mlt; o0.w = acc[3] * mlt;
    o1.x = acc[4] * mlt; o1.y = acc[5] * mlt; o1.z = acc[6] * mlt; o1.w = acc[7] * mlt;
    float* op = out + (size_t)n * EMB + lane * 8;
    nt_store_f4(op,     o0);
    nt_store_f4(op + 4, o1);
}

// =====================================================================
// Fallback (tiny ws): verified R0 fp32 kernel
// =====================================================================
__global__ __launch_bounds__(256) void pprgo_f32_kernel(
    const float* __restrict__ emb,
    const float* __restrict__ wei,
    const int*   __restrict__ nei,
    float*       __restrict__ out,
    int n_nodes)
{
    const int tid   = blockIdx.x * blockDim.x + threadIdx.x;
    const int group = tid >> 4;
    const int lane  = tid & 15;
    if (group >= n_nodes) return;
    const long base = (long)group * TOPK;
    const float w0 = wei[base + lane];
    const float w1 = wei[base + 16 + lane];
    const int   i0 = nei[base + lane];
    const int   i1 = nei[base + 16 + lane];
    const float m0 = (w0 != 0.0f) ? 1.0f : 0.0f;
    const float m1 = (w1 != 0.0f) ? 1.0f : 0.0f;
    float4 acc = make_float4(0.f, 0.f, 0.f, 0.f);
    float  cnt = 0.0f;
    #pragma unroll 8
    for (int k = 0; k < 16; ++k) {
        const int   j0 = __shfl(i0, k, 16);
        const float a0 = __shfl(m0, k, 16);
        const float4 r0 = *(const float4*)(emb + (size_t)j0 * EMB + lane * 4);
        acc.x += a0*r0.x; acc.y += a0*r0.y; acc.z += a0*r0.z; acc.w += a0*r0.w; cnt += a0;
        const int   j1 = __shfl(i1, k, 16);
        const float a1 = __shfl(m1, k, 16);
        const float4 r1 = *(const float4*)(emb + (size_t)j1 * EMB + lane * 4);
        acc.x += a1*r1.x; acc.y += a1*r1.y; acc.z += a1*r1.z; acc.w += a1*r1.w; cnt += a1;
    }
    const float sc = 1.0f / (cnt + 1e-12f);
    float4 o;
    o.x = acc.x*sc; o.y = acc.y*sc; o.z = acc.z*sc; o.w = acc.w*sc;
    *(float4*)(out + (size_t)group * EMB + lane * 4) = o;
}

extern "C" void kernel_launch(void* const* d_in, const int* in_sizes, int n_in,
                              void* d_out, int out_size, void* d_ws, size_t ws_size,
                              hipStream_t stream) {
    const float* emb = (const float*)d_in[0];   // [N, 64] fp32
    const float* wei = (const float*)d_in[1];   // [N, 32] fp32
    const int*   nei = (const int*)d_in[2];     // [N, 32] int32
    float*       out = (float*)d_out;           // [N, 1, 64] fp32

    const int n_nodes = in_sizes[1] / TOPK;     // 200000

    const size_t emb8_bytes = ((size_t)(n_nodes + 1) * EMB + 63) & ~(size_t)63; // 12.8MB
    const size_t scale_bytes = (size_t)(n_nodes + 1) * sizeof(float);           // 0.8MB
    const size_t need = emb8_bytes + scale_bytes;

    if (ws_size >= need) {
        signed char* emb8  = (signed char*)d_ws;
        float*       scale = (float*)((char*)d_ws + emb8_bytes);

        const int q_blocks = (n_nodes * 8 + 255) / 256;                // 6250
        prep_rowquant_kernel<<<q_blocks + 1, 256, 0, stream>>>(
            emb, emb8, scale, n_nodes, q_blocks);

        const int g_blocks = (n_nodes * 8 + 255) / 256;                // 6250
        gather_q8_kernel<<<g_blocks, 256, 0, stream>>>(
            emb8, scale, wei, nei, out, n_nodes);
    } else {
        const int threads = n_nodes * 16;
        pprgo_f32_kernel<<<(threads + 255) / 256, 256, 0, stream>>>(
            emb, wei, nei, out, n_nodes);
    }
}